// Round 8
// baseline (1037.893 us; speedup 1.0000x reference)
//
#include <hip/hip_runtime.h>
#include <cstdint>
#include <cstddef>

#define TDIM 4096
#define HDIM 2048
#define FDIM 1408
#define NEXP 8
#define NSLOT (TDIM * 2)
#define BK 32

typedef _Float16 half8 __attribute__((ext_vector_type(8)));
typedef _Float16 half4 __attribute__((ext_vector_type(4)));
typedef float floatx4 __attribute__((ext_vector_type(4)));

#define AS1 __attribute__((address_space(1)))
#define AS3 __attribute__((address_space(3)))

// async global->LDS, 16B per lane; lds dst is wave-uniform base (+lane*16B scatter)
__device__ __forceinline__ void g2l16(const _Float16* g, _Float16* l) {
  __builtin_amdgcn_global_load_lds((const AS1 unsigned*)g, (AS3 unsigned*)l, 16, 0, 0);
}

// compiler-level memory fence (zero instructions): stops LDS reads/stage ops
// from being scheduled across a raw s_barrier by the compiler
#define CFENCE() asm volatile("" ::: "memory")

// ---------------- ws layout (bytes) ----------------
static constexpr size_t ws_align(size_t x) { return (x + 511) & ~(size_t)511; }
static constexpr size_t WS_XB     = 0;                                  // f16 [TDIM][HDIM]
static constexpr size_t WS_ACT_S  = WS_XB    + (size_t)TDIM * HDIM * 2; // f16 [TDIM][FDIM]
static constexpr size_t WS_ACT_R  = WS_ACT_S + (size_t)TDIM * FDIM * 2; // f16 [NSLOT][FDIM]
static constexpr size_t WS_TOKE   = WS_ACT_R + (size_t)NSLOT * FDIM * 2;// int  [TDIM][2]
static constexpr size_t WS_TOKG   = WS_TOKE  + (size_t)TDIM * 2 * 4;    // f32  [TDIM][2]
static constexpr size_t WS_SLOTT  = WS_TOKG  + (size_t)TDIM * 2 * 4;    // int  [NSLOT]
static constexpr size_t WS_SLOTG  = WS_SLOTT + (size_t)NSLOT * 4;       // f32  [NSLOT]
static constexpr size_t WS_COUNTS = WS_SLOTG + (size_t)NSLOT * 4;       // int  [NEXP] (64B slot)
static constexpr size_t WS_FILL   = WS_COUNTS + 64;                     // int  [NEXP] (64B slot)
static constexpr size_t WS_OFFS   = WS_FILL   + 64;                     // int  [NEXP]
static constexpr size_t WS_WS1H   = ws_align(WS_OFFS + 64);
static constexpr size_t WS_WS3H   = WS_WS1H + (size_t)FDIM * HDIM * 2;
static constexpr size_t WS_WS2H   = WS_WS3H + (size_t)FDIM * HDIM * 2;
static constexpr size_t WS_WE1H   = WS_WS2H + (size_t)HDIM * FDIM * 2;
static constexpr size_t WS_WE3H   = WS_WE1H + (size_t)NEXP * FDIM * HDIM * 2;
static constexpr size_t WS_WE2H   = WS_WE3H + (size_t)NEXP * FDIM * HDIM * 2;
static constexpr size_t WS_END    = WS_WE2H + (size_t)NEXP * HDIM * FDIM * 2;

// ---------------- small kernels ----------------

__global__ void zero_meta_kernel(int* __restrict__ counts) {
  if (threadIdx.x < 32) counts[threadIdx.x] = 0;
}

// fp32 -> f16 for 3 equal-size tensors (blockIdx.y selects), 8 elems/thread
__global__ void cvt3_kernel(const float* __restrict__ s0, const float* __restrict__ s1,
                            const float* __restrict__ s2, _Float16* __restrict__ d0,
                            _Float16* __restrict__ d1, _Float16* __restrict__ d2) {
  const float* s;
  _Float16* d;
  if (blockIdx.y == 0)      { s = s0; d = d0; }
  else if (blockIdx.y == 1) { s = s1; d = d1; }
  else                      { s = s2; d = d2; }
  size_t i = ((size_t)blockIdx.x * 256 + threadIdx.x) * 8;
  float4 a = *(const float4*)(s + i);
  float4 b = *(const float4*)(s + i + 4);
  half8 h;
  h[0] = (_Float16)a.x; h[1] = (_Float16)a.y; h[2] = (_Float16)a.z; h[3] = (_Float16)a.w;
  h[4] = (_Float16)b.x; h[5] = (_Float16)b.y; h[6] = (_Float16)b.z; h[7] = (_Float16)b.w;
  *(half8*)(d + i) = h;
}

// one wave per token: fp32 routing (discrete decisions must match reference).
// Also emits the f16 copy of x (row is already in registers) -> saves a cvt pass.
__global__ void gate_kernel(const float* __restrict__ x, const float* __restrict__ gw,
                            const float* __restrict__ bias, _Float16* __restrict__ xb,
                            int* __restrict__ toke, float* __restrict__ tokg,
                            int* __restrict__ counts) {
  const int wid  = blockIdx.x * 4 + (threadIdx.x >> 6);
  const int lane = threadIdx.x & 63;
  const float4* xv = (const float4*)(x + (size_t)wid * HDIM);
  const float4* gv = (const float4*)gw;
  _Float16* xrow = xb + (size_t)wid * HDIM;
  float acc[NEXP];
#pragma unroll
  for (int e = 0; e < NEXP; ++e) acc[e] = 0.f;
#pragma unroll
  for (int i = 0; i < 8; ++i) {
    float4 xq = xv[lane + 64 * i];
    half4 hq;
    hq[0] = (_Float16)xq.x; hq[1] = (_Float16)xq.y;
    hq[2] = (_Float16)xq.z; hq[3] = (_Float16)xq.w;
    *(half4*)(xrow + 4 * (lane + 64 * i)) = hq;
#pragma unroll
    for (int e = 0; e < NEXP; ++e) {
      float4 gq = gv[e * 512 + lane + 64 * i];
      acc[e] += xq.x * gq.x + xq.y * gq.y + xq.z * gq.z + xq.w * gq.w;
    }
  }
#pragma unroll
  for (int e = 0; e < NEXP; ++e) {
    float v = acc[e];
    for (int off = 32; off; off >>= 1) v += __shfl_xor(v, off);
    acc[e] = v;
  }
  if (lane == 0) {
    float s[NEXP], r[NEXP];
#pragma unroll
    for (int e = 0; e < NEXP; ++e) {
      s[e] = 1.f / (1.f + __expf(-acc[e]));
      r[e] = s[e] + bias[e];
    }
    int e0 = 0;
#pragma unroll
    for (int e = 1; e < NEXP; ++e) if (r[e] > r[e0]) e0 = e;
    int e1 = -1;
#pragma unroll
    for (int e = 0; e < NEXP; ++e) if (e != e0 && (e1 < 0 || r[e] > r[e1])) e1 = e;
    float g0 = s[e0], g1 = s[e1];
    float inv = 1.f / (g0 + g1);
    toke[wid * 2]     = e0;
    toke[wid * 2 + 1] = e1;
    tokg[wid * 2]     = g0 * inv;
    tokg[wid * 2 + 1] = g1 * inv;
    atomicAdd(&counts[e0], 1);
    atomicAdd(&counts[e1], 1);
  }
}

__global__ void offsets_kernel(const int* __restrict__ counts, int* __restrict__ offs) {
  if (threadIdx.x == 0) {
    int o = 0;
    for (int e = 0; e < NEXP; ++e) { offs[e] = o; o += counts[e]; }
  }
}

__global__ void scatter_kernel(const int* __restrict__ toke, const float* __restrict__ tokg,
                               const int* __restrict__ offs, int* __restrict__ fill,
                               int* __restrict__ slott, float* __restrict__ slotg) {
  int t = blockIdx.x * 256 + threadIdx.x;
#pragma unroll
  for (int j = 0; j < 2; ++j) {
    int e = toke[t * 2 + j];
    float g = tokg[t * 2 + j];
    int p = offs[e] + atomicAdd(&fill[e], 1);
    slott[p] = t;
    slotg[p] = g;
  }
}

// ---------------- GEMM kernels ----------------
// 128x128 tile, BK=32, double-buffered LDS, 256 thr (4 waves, 2x2 of 64x64),
// MFMA 16x16x32 f16.
// COUNTED-VMCNT 2-DEEP PIPELINE (T4): stage(t+2) is issued after a
// readers-done barrier; we then wait only vmcnt(N) (N = loads/wave for ONE
// tile) so the newest tile's loads stay in flight ACROSS the barrier and
// tile t+1's loads get a full iteration of MFMA+ds_read to land. Never a
// vmcnt(0) drain in the steady-state loop (the __syncthreads() drain was
// the measured 19%-MfmaUtil limiter).
// Swizzle: row is 64B = 4 chunks of 16B. LDS[row][c] = G[row][c ^ ((row>>1)&3)]
// (applied at the GLOBAL source; LDS dest stays linear for global_load_lds).
// Readback chunk' = quad ^ ((row>>1)&3) -> conflict-free ds_read_b128.
// blockIdx.z: 0 = shared expert (all tokens, dense), 1..8 = routed expert z-1.

__global__ __launch_bounds__(256) void up_kernel(
    const _Float16* __restrict__ xb,
    const _Float16* __restrict__ ws1h, const _Float16* __restrict__ ws3h,
    const _Float16* __restrict__ we1h, const _Float16* __restrict__ we3h,
    _Float16* __restrict__ acts, _Float16* __restrict__ actr,
    const int* __restrict__ counts, const int* __restrict__ offs,
    const int* __restrict__ slott) {
  const int z = blockIdx.z;
  int cnt = TDIM, base = 0;
  const _Float16* __restrict__ W1 = ws1h;
  const _Float16* __restrict__ W3 = ws3h;
  _Float16* __restrict__ act = acts;
  bool gather = false;
  if (z > 0) {
    const int e = z - 1;
    cnt = counts[e];
    base = offs[e];
    if ((int)(blockIdx.y * 128) >= cnt) return;
    W1 = we1h + (size_t)e * FDIM * HDIM;
    W3 = we3h + (size_t)e * FDIM * HDIM;
    act = actr;
    gather = true;
  }
  const int m0 = blockIdx.y * 128, n0 = blockIdx.x * 128;

  __shared__ _Float16 As[2][128 * BK];
  __shared__ _Float16 B1s[2][128 * BK];
  __shared__ _Float16 B3s[2][128 * BK];

  const int tid = threadIdx.x, lane = tid & 63, wv = tid >> 6;
  const int wm = wv >> 1, wn = wv & 1;
  const int lrow = lane & 15, quad = lane >> 4;

  // staging: wave wv call j covers tile rows wv*32+j*16 .. +16 (1KB each)
  const _Float16 *srcA[2], *srcB1[2], *srcB3[2];
  int lb_[2];
#pragma unroll
  for (int j = 0; j < 2; ++j) {
    const int rr = wv * 32 + j * 16 + (lane >> 2);
    const int gc = ((lane & 3) ^ ((rr >> 1) & 3)) * 8;  // pre-swizzled source chunk
    const int m = m0 + rr;
    int tok;
    if (gather) tok = slott[base + (m < cnt ? m : cnt - 1)];
    else tok = m;
    srcA[j]  = xb + (size_t)tok * HDIM + gc;
    srcB1[j] = W1 + (size_t)(n0 + rr) * HDIM + gc;
    srcB3[j] = W3 + (size_t)(n0 + rr) * HDIM + gc;
    lb_[j] = (wv * 32 + j * 16) * BK;
  }

  // 6 g2l16 per wave per tile -> steady-state wait is vmcnt(6)
  auto stage = [&](int tt, int b) {
    const int k0 = tt * BK;
#pragma unroll
    for (int j = 0; j < 2; ++j) {
      g2l16(srcA[j] + k0,  &As[b][lb_[j]]);
      g2l16(srcB1[j] + k0, &B1s[b][lb_[j]]);
      g2l16(srcB3[j] + k0, &B3s[b][lb_[j]]);
    }
  };

  floatx4 acc1[4][4] = {};
  floatx4 acc3[4][4] = {};
  const int cA = (quad ^ ((lrow >> 1) & 3)) * 8;  // swizzled read chunk (halfs)

  constexpr int NT = HDIM / BK;  // 64
  // prologue: 2-deep prefetch
  stage(0, 0);
  stage(1, 1);
  asm volatile("s_waitcnt vmcnt(6)" ::: "memory");  // tile 0 (this wave) landed
  CFENCE(); __builtin_amdgcn_s_barrier(); CFENCE(); // all waves' tile 0 landed

  int cur = 0;
  for (int t = 0; t < NT; ++t) {
    half8 af[4], b1f[4], b3f[4];
#pragma unroll
    for (int i = 0; i < 4; ++i)
      af[i] = *(const half8*)&As[cur][(wm * 64 + i * 16 + lrow) * BK + cA];
#pragma unroll
    for (int i = 0; i < 4; ++i) {
      b1f[i] = *(const half8*)&B1s[cur][(wn * 64 + i * 16 + lrow) * BK + cA];
      b3f[i] = *(const half8*)&B3s[cur][(wn * 64 + i * 16 + lrow) * BK + cA];
    }
#pragma unroll
    for (int ms = 0; ms < 4; ++ms)
#pragma unroll
      for (int ns = 0; ns < 4; ++ns) {
        acc1[ms][ns] = __builtin_amdgcn_mfma_f32_16x16x32_f16(af[ms], b1f[ns], acc1[ms][ns], 0, 0, 0);
        acc3[ms][ns] = __builtin_amdgcn_mfma_f32_16x16x32_f16(af[ms], b3f[ns], acc3[ms][ns], 0, 0, 0);
      }
    // readers of buf[cur] done (lgkm drained by MFMA deps)
    CFENCE(); __builtin_amdgcn_s_barrier(); CFENCE();
    if (t + 2 < NT) {
      stage(t + 2, cur);                                // overwrite cur (2 ahead)
      asm volatile("s_waitcnt vmcnt(6)" ::: "memory");  // tile t+1 landed; t+2 in flight
    } else {
      asm volatile("s_waitcnt vmcnt(0)" ::: "memory");  // epilogue drain
    }
    CFENCE(); __builtin_amdgcn_s_barrier(); CFENCE();   // buf[cur^1] ready for all
    cur ^= 1;
  }

  // epilogue: silu(h1)*h3 (C/D layout: col=lane&15, row=quad*4+reg)
#pragma unroll
  for (int ms = 0; ms < 4; ++ms)
#pragma unroll
    for (int ns = 0; ns < 4; ++ns)
#pragma unroll
      for (int r = 0; r < 4; ++r) {
        float h1 = acc1[ms][ns][r];
        float h3 = acc3[ms][ns][r];
        float a = h1 / (1.f + __expf(-h1)) * h3;
        const int rl = wm * 64 + ms * 16 + quad * 4 + r;
        const int f = n0 + wn * 64 + ns * 16 + lrow;
        const int m = m0 + rl;
        if (gather) {
          if (m < cnt) act[(size_t)(base + m) * FDIM + f] = (_Float16)a;
        } else {
          act[(size_t)m * FDIM + f] = (_Float16)a;
        }
      }
}

// down: A (f16 act) @ W2^T; out pre-zeroed, all paths atomicAdd (order-free)
__global__ __launch_bounds__(256) void down_kernel(
    const _Float16* __restrict__ acts, const _Float16* __restrict__ actr,
    const _Float16* __restrict__ ws2h, const _Float16* __restrict__ we2h,
    float* __restrict__ out,
    const int* __restrict__ counts, const int* __restrict__ offs,
    const int* __restrict__ slott, const float* __restrict__ slotg) {
  const int z = blockIdx.z;
  int cnt = TDIM, base = 0;
  const _Float16* __restrict__ A = acts;
  const _Float16* __restrict__ W = ws2h;
  bool gather = false;
  if (z > 0) {
    const int e = z - 1;
    cnt = counts[e];
    base = offs[e];
    if ((int)(blockIdx.y * 128) >= cnt) return;
    A = actr;
    W = we2h + (size_t)e * HDIM * FDIM;
    gather = true;
  }
  const int m0 = blockIdx.y * 128, n0 = blockIdx.x * 128;

  __shared__ _Float16 As[2][128 * BK];
  __shared__ _Float16 Bs[2][128 * BK];

  const int tid = threadIdx.x, lane = tid & 63, wv = tid >> 6;
  const int wm = wv >> 1, wn = wv & 1;
  const int lrow = lane & 15, quad = lane >> 4;

  const _Float16 *srcA[2], *srcB[2];
  int lb_[2];
#pragma unroll
  for (int j = 0; j < 2; ++j) {
    const int rr = wv * 32 + j * 16 + (lane >> 2);
    const int gc = ((lane & 3) ^ ((rr >> 1) & 3)) * 8;
    const int m = m0 + rr;
    int srow;
    if (gather) srow = base + (m < cnt ? m : cnt - 1);
    else srow = m;
    srcA[j] = A + (size_t)srow * FDIM + gc;
    srcB[j] = W + (size_t)(n0 + rr) * FDIM + gc;
    lb_[j] = (wv * 32 + j * 16) * BK;
  }

  // 4 g2l16 per wave per tile -> steady-state wait is vmcnt(4)
  auto stage = [&](int tt, int b) {
    const int k0 = tt * BK;
#pragma unroll
    for (int j = 0; j < 2; ++j) {
      g2l16(srcA[j] + k0, &As[b][lb_[j]]);
      g2l16(srcB[j] + k0, &Bs[b][lb_[j]]);
    }
  };

  floatx4 acc[4][4] = {};
  const int cA = (quad ^ ((lrow >> 1) & 3)) * 8;

  constexpr int NT = FDIM / BK;  // 44
  stage(0, 0);
  stage(1, 1);
  asm volatile("s_waitcnt vmcnt(4)" ::: "memory");
  CFENCE(); __builtin_amdgcn_s_barrier(); CFENCE();

  int cur = 0;
  for (int t = 0; t < NT; ++t) {
    half8 af[4], bf[4];
#pragma unroll
    for (int i = 0; i < 4; ++i)
      af[i] = *(const half8*)&As[cur][(wm * 64 + i * 16 + lrow) * BK + cA];
#pragma unroll
    for (int i = 0; i < 4; ++i)
      bf[i] = *(const half8*)&Bs[cur][(wn * 64 + i * 16 + lrow) * BK + cA];
#pragma unroll
    for (int ms = 0; ms < 4; ++ms)
#pragma unroll
      for (int ns = 0; ns < 4; ++ns)
        acc[ms][ns] = __builtin_amdgcn_mfma_f32_16x16x32_f16(af[ms], bf[ns], acc[ms][ns], 0, 0, 0);
    CFENCE(); __builtin_amdgcn_s_barrier(); CFENCE();
    if (t + 2 < NT) {
      stage(t + 2, cur);
      asm volatile("s_waitcnt vmcnt(4)" ::: "memory");
    } else {
      asm volatile("s_waitcnt vmcnt(0)" ::: "memory");
    }
    CFENCE(); __builtin_amdgcn_s_barrier(); CFENCE();
    cur ^= 1;
  }

#pragma unroll
  for (int ms = 0; ms < 4; ++ms)
#pragma unroll
    for (int ns = 0; ns < 4; ++ns)
#pragma unroll
      for (int r = 0; r < 4; ++r) {
        float v = acc[ms][ns][r];
        const int rl = wm * 64 + ms * 16 + quad * 4 + r;
        const int h = n0 + wn * 64 + ns * 16 + lrow;
        const int m = m0 + rl;
        if (gather) {
          if (m < cnt) {
            const int sl = base + m;
            atomicAdd(&out[(size_t)slott[sl] * HDIM + h], v * slotg[sl]);
          }
        } else {
          atomicAdd(&out[(size_t)m * HDIM + h], v);
        }
      }
}

// ---------------- launcher ----------------

extern "C" void kernel_launch(void* const* d_in, const int* in_sizes, int n_in,
                              void* d_out, int out_size, void* d_ws, size_t ws_size,
                              hipStream_t stream) {
  const float* x    = (const float*)d_in[0];
  const float* gw   = (const float*)d_in[1];
  const float* bias = (const float*)d_in[2];
  const float* ws1  = (const float*)d_in[3];
  const float* ws2  = (const float*)d_in[4];
  const float* ws3  = (const float*)d_in[5];
  const float* we1  = (const float*)d_in[6];
  const float* we2  = (const float*)d_in[7];
  const float* we3  = (const float*)d_in[8];
  float* out = (float*)d_out;

  char* ws = (char*)d_ws;
  _Float16* xb   = (_Float16*)(ws + WS_XB);
  _Float16* acts = (_Float16*)(ws + WS_ACT_S);
  _Float16* actr = (_Float16*)(ws + WS_ACT_R);
  int*   toke  = (int*)(ws + WS_TOKE);
  float* tokg  = (float*)(ws + WS_TOKG);
  int*   slott = (int*)(ws + WS_SLOTT);
  float* slotg = (float*)(ws + WS_SLOTG);
  int* counts  = (int*)(ws + WS_COUNTS);
  int* fill    = (int*)(ws + WS_FILL);
  int* offs    = (int*)(ws + WS_OFFS);
  _Float16* ws1h = (_Float16*)(ws + WS_WS1H);
  _Float16* ws3h = (_Float16*)(ws + WS_WS3H);
  _Float16* ws2h = (_Float16*)(ws + WS_WS2H);
  _Float16* we1h = (_Float16*)(ws + WS_WE1H);
  _Float16* we3h = (_Float16*)(ws + WS_WE3H);
  _Float16* we2h = (_Float16*)(ws + WS_WE2H);

  hipLaunchKernelGGL(zero_meta_kernel, dim3(1), dim3(64), 0, stream, counts);
  hipLaunchKernelGGL(gate_kernel, dim3(1024), dim3(256), 0, stream, x, gw, bias, xb, toke, tokg, counts);
  hipLaunchKernelGGL(offsets_kernel, dim3(1), dim3(64), 0, stream, counts, offs);
  hipLaunchKernelGGL(scatter_kernel, dim3(16), dim3(256), 0, stream, toke, tokg, offs, fill, slott, slotg);

  constexpr int GS = (FDIM * HDIM) / 2048;           // 1408
  constexpr int GR = (NEXP * FDIM * HDIM) / 2048;    // 11264
  hipLaunchKernelGGL(cvt3_kernel, dim3(GS, 3), dim3(256), 0, stream, ws1, ws3, ws2, ws1h, ws3h, ws2h);
  hipLaunchKernelGGL(cvt3_kernel, dim3(GR, 3), dim3(256), 0, stream, we1, we3, we2, we1h, we3h, we2h);

  hipMemsetAsync(out, 0, (size_t)TDIM * HDIM * sizeof(float), stream);

  // z = 0: shared expert (dense over all tokens); z = 1..8: routed expert z-1
  hipLaunchKernelGGL(up_kernel, dim3(FDIM / 128, TDIM / 128, NEXP + 1), dim3(256), 0, stream,
                     xb, ws1h, ws3h, we1h, we3h, acts, actr, counts, offs, slott);
  hipLaunchKernelGGL(down_kernel, dim3(HDIM / 128, TDIM / 128, NEXP + 1), dim3(256), 0, stream,
                     acts, actr, ws2h, we2h, out, counts, offs, slott, slotg);
}

// Round 9
// 966.734 us; speedup vs baseline: 1.0736x; 1.0736x over previous
//
#include <hip/hip_runtime.h>
#include <cstdint>
#include <cstddef>

#define TDIM 4096
#define HDIM 2048
#define FDIM 1408
#define NEXP 8
#define NSLOT (TDIM * 2)
#define BK 32

typedef _Float16 half8 __attribute__((ext_vector_type(8)));
typedef _Float16 half4 __attribute__((ext_vector_type(4)));
typedef float floatx4 __attribute__((ext_vector_type(4)));

#define AS1 __attribute__((address_space(1)))
#define AS3 __attribute__((address_space(3)))

// async global->LDS, 16B per lane; lds dst is wave-uniform base (+lane*16B scatter)
__device__ __forceinline__ void g2l16(const _Float16* g, _Float16* l) {
  __builtin_amdgcn_global_load_lds((const AS1 unsigned*)g, (AS3 unsigned*)l, 16, 0, 0);
}

// ---------------- ws layout (bytes) ----------------
static constexpr size_t ws_align(size_t x) { return (x + 511) & ~(size_t)511; }
static constexpr size_t WS_XB     = 0;                                  // f16 [TDIM][HDIM]
static constexpr size_t WS_ACT_S  = WS_XB    + (size_t)TDIM * HDIM * 2; // f16 [TDIM][FDIM]
static constexpr size_t WS_ACT_R  = WS_ACT_S + (size_t)TDIM * FDIM * 2; // f16 [NSLOT][FDIM]
static constexpr size_t WS_TOKE   = WS_ACT_R + (size_t)NSLOT * FDIM * 2;// int  [TDIM][2]
static constexpr size_t WS_TOKG   = WS_TOKE  + (size_t)TDIM * 2 * 4;    // f32  [TDIM][2]
static constexpr size_t WS_SLOTT  = WS_TOKG  + (size_t)TDIM * 2 * 4;    // int  [NSLOT]
static constexpr size_t WS_SLOTG  = WS_SLOTT + (size_t)NSLOT * 4;       // f32  [NSLOT]
static constexpr size_t WS_COUNTS = WS_SLOTG + (size_t)NSLOT * 4;       // int  [NEXP] (64B slot)
static constexpr size_t WS_FILL   = WS_COUNTS + 64;                     // int  [NEXP] (64B slot)
static constexpr size_t WS_OFFS   = WS_FILL   + 64;                     // int  [NEXP]
static constexpr size_t WS_WS1H   = ws_align(WS_OFFS + 64);
static constexpr size_t WS_WS3H   = WS_WS1H + (size_t)FDIM * HDIM * 2;
static constexpr size_t WS_WS2H   = WS_WS3H + (size_t)FDIM * HDIM * 2;
static constexpr size_t WS_WE1H   = WS_WS2H + (size_t)HDIM * FDIM * 2;
static constexpr size_t WS_WE3H   = WS_WE1H + (size_t)NEXP * FDIM * HDIM * 2;
static constexpr size_t WS_WE2H   = WS_WE3H + (size_t)NEXP * FDIM * HDIM * 2;
static constexpr size_t WS_END    = WS_WE2H + (size_t)NEXP * HDIM * FDIM * 2;

// ---------------- small kernels ----------------

__global__ void zero_meta_kernel(int* __restrict__ counts) {
  if (threadIdx.x < 32) counts[threadIdx.x] = 0;
}

// fp32 -> f16 for 3 equal-size tensors (blockIdx.y selects), 8 elems/thread
__global__ void cvt3_kernel(const float* __restrict__ s0, const float* __restrict__ s1,
                            const float* __restrict__ s2, _Float16* __restrict__ d0,
                            _Float16* __restrict__ d1, _Float16* __restrict__ d2) {
  const float* s;
  _Float16* d;
  if (blockIdx.y == 0)      { s = s0; d = d0; }
  else if (blockIdx.y == 1) { s = s1; d = d1; }
  else                      { s = s2; d = d2; }
  size_t i = ((size_t)blockIdx.x * 256 + threadIdx.x) * 8;
  float4 a = *(const float4*)(s + i);
  float4 b = *(const float4*)(s + i + 4);
  half8 h;
  h[0] = (_Float16)a.x; h[1] = (_Float16)a.y; h[2] = (_Float16)a.z; h[3] = (_Float16)a.w;
  h[4] = (_Float16)b.x; h[5] = (_Float16)b.y; h[6] = (_Float16)b.z; h[7] = (_Float16)b.w;
  *(half8*)(d + i) = h;
}

// one wave per token: fp32 routing (discrete decisions must match reference).
// Also emits the f16 copy of x (row is already in registers) -> saves a cvt pass.
__global__ void gate_kernel(const float* __restrict__ x, const float* __restrict__ gw,
                            const float* __restrict__ bias, _Float16* __restrict__ xb,
                            int* __restrict__ toke, float* __restrict__ tokg,
                            int* __restrict__ counts) {
  const int wid  = blockIdx.x * 4 + (threadIdx.x >> 6);
  const int lane = threadIdx.x & 63;
  const float4* xv = (const float4*)(x + (size_t)wid * HDIM);
  const float4* gv = (const float4*)gw;
  _Float16* xrow = xb + (size_t)wid * HDIM;
  float acc[NEXP];
#pragma unroll
  for (int e = 0; e < NEXP; ++e) acc[e] = 0.f;
#pragma unroll
  for (int i = 0; i < 8; ++i) {
    float4 xq = xv[lane + 64 * i];
    half4 hq;
    hq[0] = (_Float16)xq.x; hq[1] = (_Float16)xq.y;
    hq[2] = (_Float16)xq.z; hq[3] = (_Float16)xq.w;
    *(half4*)(xrow + 4 * (lane + 64 * i)) = hq;
#pragma unroll
    for (int e = 0; e < NEXP; ++e) {
      float4 gq = gv[e * 512 + lane + 64 * i];
      acc[e] += xq.x * gq.x + xq.y * gq.y + xq.z * gq.z + xq.w * gq.w;
    }
  }
#pragma unroll
  for (int e = 0; e < NEXP; ++e) {
    float v = acc[e];
    for (int off = 32; off; off >>= 1) v += __shfl_xor(v, off);
    acc[e] = v;
  }
  if (lane == 0) {
    float s[NEXP], r[NEXP];
#pragma unroll
    for (int e = 0; e < NEXP; ++e) {
      s[e] = 1.f / (1.f + __expf(-acc[e]));
      r[e] = s[e] + bias[e];
    }
    int e0 = 0;
#pragma unroll
    for (int e = 1; e < NEXP; ++e) if (r[e] > r[e0]) e0 = e;
    int e1 = -1;
#pragma unroll
    for (int e = 0; e < NEXP; ++e) if (e != e0 && (e1 < 0 || r[e] > r[e1])) e1 = e;
    float g0 = s[e0], g1 = s[e1];
    float inv = 1.f / (g0 + g1);
    toke[wid * 2]     = e0;
    toke[wid * 2 + 1] = e1;
    tokg[wid * 2]     = g0 * inv;
    tokg[wid * 2 + 1] = g1 * inv;
    atomicAdd(&counts[e0], 1);
    atomicAdd(&counts[e1], 1);
  }
}

__global__ void offsets_kernel(const int* __restrict__ counts, int* __restrict__ offs) {
  if (threadIdx.x == 0) {
    int o = 0;
    for (int e = 0; e < NEXP; ++e) { offs[e] = o; o += counts[e]; }
  }
}

__global__ void scatter_kernel(const int* __restrict__ toke, const float* __restrict__ tokg,
                               const int* __restrict__ offs, int* __restrict__ fill,
                               int* __restrict__ slott, float* __restrict__ slotg) {
  int t = blockIdx.x * 256 + threadIdx.x;
#pragma unroll
  for (int j = 0; j < 2; ++j) {
    int e = toke[t * 2 + j];
    float g = tokg[t * 2 + j];
    int p = offs[e] + atomicAdd(&fill[e], 1);
    slott[p] = t;
    slotg[p] = g;
  }
}

// ---------------- GEMM kernels ----------------
// 128x128 tile, BK=32, double-buffered LDS, 256 thr (4 waves, 2x2 of 64x64),
// MFMA 16x16x32 f16. Round-7 schedule (measured best): stage(t+1) issued at
// TOP of iteration (overlaps MFMA), single __syncthreads per K-step.
// NEW (T1): XCD group-locality swizzle. HW dispatch maps hw-block i -> XCD
// i%8. We remap so the GX blocks sharing the same A-rows (one n-row group)
// are consecutive slots on ONE XCD -> A is fetched once into that XCD's L2
// and the other GX-1 blocks hit it (~200cy) instead of re-fetching via
// L3/HBM (~400-900cy). Groups are dealt round-robin across XCDs -> load
// balance (incl. early-return gather blocks) is preserved.
// Swizzle math (bijective): k=i%8, s=i/8; g = k + 8*(s/GX); lid = g*GX + s%GX.
// LDS chunk-XOR swizzle unchanged: LDS[row][c] = G[row][c ^ ((row>>1)&3)],
// readback chunk' = quad ^ ((lrow>>1)&3) -> conflict-free ds_read_b128.
// bz: 0 = shared expert (all tokens, dense), 1..8 = routed expert bz-1.

__global__ __launch_bounds__(256) void up_kernel(
    const _Float16* __restrict__ xb,
    const _Float16* __restrict__ ws1h, const _Float16* __restrict__ ws3h,
    const _Float16* __restrict__ we1h, const _Float16* __restrict__ we3h,
    _Float16* __restrict__ acts, _Float16* __restrict__ actr,
    const int* __restrict__ counts, const int* __restrict__ offs,
    const int* __restrict__ slott) {
  constexpr int GX = FDIM / 128;   // 11
  constexpr int GY = TDIM / 128;   // 32
  // bijective XCD group swizzle (all-SGPR)
  const int orig = blockIdx.x + GX * (blockIdx.y + GY * blockIdx.z);
  const int k8 = orig & 7, s = orig >> 3;
  const int g = k8 + 8 * (s / GX);
  const int lid = g * GX + (s % GX);
  const int bx = lid % GX;
  const int by = (lid / GX) % GY;
  const int bz = lid / (GX * GY);

  int cnt = TDIM, base = 0;
  const _Float16* __restrict__ W1 = ws1h;
  const _Float16* __restrict__ W3 = ws3h;
  _Float16* __restrict__ act = acts;
  bool gather = false;
  if (bz > 0) {
    const int e = bz - 1;
    cnt = counts[e];
    base = offs[e];
    if ((int)(by * 128) >= cnt) return;
    W1 = we1h + (size_t)e * FDIM * HDIM;
    W3 = we3h + (size_t)e * FDIM * HDIM;
    act = actr;
    gather = true;
  }
  const int m0 = by * 128, n0 = bx * 128;

  __shared__ _Float16 As[2][128 * BK];
  __shared__ _Float16 B1s[2][128 * BK];
  __shared__ _Float16 B3s[2][128 * BK];

  const int tid = threadIdx.x, lane = tid & 63, wv = tid >> 6;
  const int wm = wv >> 1, wn = wv & 1;
  const int lrow = lane & 15, quad = lane >> 4;

  // staging: wave wv call j covers tile rows wv*32+j*16 .. +16 (1KB each)
  const _Float16 *srcA[2], *srcB1[2], *srcB3[2];
#pragma unroll
  for (int j = 0; j < 2; ++j) {
    const int rr = wv * 32 + j * 16 + (lane >> 2);
    const int gc = ((lane & 3) ^ ((rr >> 1) & 3)) * 8;  // pre-swizzled source chunk
    const int m = m0 + rr;
    int tok;
    if (gather) tok = slott[base + (m < cnt ? m : cnt - 1)];
    else tok = m;
    srcA[j]  = xb + (size_t)tok * HDIM + gc;
    srcB1[j] = W1 + (size_t)(n0 + rr) * HDIM + gc;
    srcB3[j] = W3 + (size_t)(n0 + rr) * HDIM + gc;
  }

  floatx4 acc1[4][4] = {};
  floatx4 acc3[4][4] = {};
  const int cA = (quad ^ ((lrow >> 1) & 3)) * 8;  // swizzled read chunk (halfs)

  // prologue: stage tile 0
#pragma unroll
  for (int j = 0; j < 2; ++j) {
    const int lb = (wv * 32 + j * 16) * BK;
    g2l16(srcA[j],  &As[0][lb]);
    g2l16(srcB1[j], &B1s[0][lb]);
    g2l16(srcB3[j], &B3s[0][lb]);
  }
  __syncthreads();

  for (int t = 0; t < HDIM / BK; ++t) {
    const int cur = t & 1;
    if (t + 1 < HDIM / BK) {  // issue next-tile loads first (hide under MFMA)
      const int k0 = (t + 1) * BK;
#pragma unroll
      for (int j = 0; j < 2; ++j) {
        const int lb = (wv * 32 + j * 16) * BK;
        g2l16(srcA[j] + k0,  &As[cur ^ 1][lb]);
        g2l16(srcB1[j] + k0, &B1s[cur ^ 1][lb]);
        g2l16(srcB3[j] + k0, &B3s[cur ^ 1][lb]);
      }
    }
    half8 af[4], b1f[4], b3f[4];
#pragma unroll
    for (int i = 0; i < 4; ++i)
      af[i] = *(const half8*)&As[cur][(wm * 64 + i * 16 + lrow) * BK + cA];
#pragma unroll
    for (int i = 0; i < 4; ++i) {
      b1f[i] = *(const half8*)&B1s[cur][(wn * 64 + i * 16 + lrow) * BK + cA];
      b3f[i] = *(const half8*)&B3s[cur][(wn * 64 + i * 16 + lrow) * BK + cA];
    }
#pragma unroll
    for (int ms = 0; ms < 4; ++ms)
#pragma unroll
      for (int ns = 0; ns < 4; ++ns) {
        acc1[ms][ns] = __builtin_amdgcn_mfma_f32_16x16x32_f16(af[ms], b1f[ns], acc1[ms][ns], 0, 0, 0);
        acc3[ms][ns] = __builtin_amdgcn_mfma_f32_16x16x32_f16(af[ms], b3f[ns], acc3[ms][ns], 0, 0, 0);
      }
    __syncthreads();  // drains vmcnt: next buffer staged; all reads of cur done
  }

  // epilogue: silu(h1)*h3 (C/D layout: col=lane&15, row=quad*4+reg)
#pragma unroll
  for (int ms = 0; ms < 4; ++ms)
#pragma unroll
    for (int ns = 0; ns < 4; ++ns)
#pragma unroll
      for (int r = 0; r < 4; ++r) {
        float h1 = acc1[ms][ns][r];
        float h3 = acc3[ms][ns][r];
        float a = h1 / (1.f + __expf(-h1)) * h3;
        const int rl = wm * 64 + ms * 16 + quad * 4 + r;
        const int f = n0 + wn * 64 + ns * 16 + lrow;
        const int m = m0 + rl;
        if (gather) {
          if (m < cnt) act[(size_t)(base + m) * FDIM + f] = (_Float16)a;
        } else {
          act[(size_t)m * FDIM + f] = (_Float16)a;
        }
      }
}

// down: A (f16 act) @ W2^T; out pre-zeroed, all paths atomicAdd (order-free)
__global__ __launch_bounds__(256) void down_kernel(
    const _Float16* __restrict__ acts, const _Float16* __restrict__ actr,
    const _Float16* __restrict__ ws2h, const _Float16* __restrict__ we2h,
    float* __restrict__ out,
    const int* __restrict__ counts, const int* __restrict__ offs,
    const int* __restrict__ slott, const float* __restrict__ slotg) {
  constexpr int GX = HDIM / 128;   // 16
  constexpr int GY = TDIM / 128;   // 32
  const int orig = blockIdx.x + GX * (blockIdx.y + GY * blockIdx.z);
  const int k8 = orig & 7, s = orig >> 3;
  const int g = k8 + 8 * (s / GX);
  const int lid = g * GX + (s % GX);
  const int bx = lid % GX;
  const int by = (lid / GX) % GY;
  const int bz = lid / (GX * GY);

  int cnt = TDIM, base = 0;
  const _Float16* __restrict__ A = acts;
  const _Float16* __restrict__ W = ws2h;
  bool gather = false;
  if (bz > 0) {
    const int e = bz - 1;
    cnt = counts[e];
    base = offs[e];
    if ((int)(by * 128) >= cnt) return;
    A = actr;
    W = we2h + (size_t)e * HDIM * FDIM;
    gather = true;
  }
  const int m0 = by * 128, n0 = bx * 128;

  __shared__ _Float16 As[2][128 * BK];
  __shared__ _Float16 Bs[2][128 * BK];

  const int tid = threadIdx.x, lane = tid & 63, wv = tid >> 6;
  const int wm = wv >> 1, wn = wv & 1;
  const int lrow = lane & 15, quad = lane >> 4;

  const _Float16 *srcA[2], *srcB[2];
#pragma unroll
  for (int j = 0; j < 2; ++j) {
    const int rr = wv * 32 + j * 16 + (lane >> 2);
    const int gc = ((lane & 3) ^ ((rr >> 1) & 3)) * 8;
    const int m = m0 + rr;
    int srow;
    if (gather) srow = base + (m < cnt ? m : cnt - 1);
    else srow = m;
    srcA[j] = A + (size_t)srow * FDIM + gc;
    srcB[j] = W + (size_t)(n0 + rr) * FDIM + gc;
  }

  floatx4 acc[4][4] = {};
  const int cA = (quad ^ ((lrow >> 1) & 3)) * 8;

#pragma unroll
  for (int j = 0; j < 2; ++j) {
    const int lb = (wv * 32 + j * 16) * BK;
    g2l16(srcA[j], &As[0][lb]);
    g2l16(srcB[j], &Bs[0][lb]);
  }
  __syncthreads();

  for (int t = 0; t < FDIM / BK; ++t) {
    const int cur = t & 1;
    if (t + 1 < FDIM / BK) {
      const int k0 = (t + 1) * BK;
#pragma unroll
      for (int j = 0; j < 2; ++j) {
        const int lb = (wv * 32 + j * 16) * BK;
        g2l16(srcA[j] + k0, &As[cur ^ 1][lb]);
        g2l16(srcB[j] + k0, &Bs[cur ^ 1][lb]);
      }
    }
    half8 af[4], bf[4];
#pragma unroll
    for (int i = 0; i < 4; ++i)
      af[i] = *(const half8*)&As[cur][(wm * 64 + i * 16 + lrow) * BK + cA];
#pragma unroll
    for (int i = 0; i < 4; ++i)
      bf[i] = *(const half8*)&Bs[cur][(wn * 64 + i * 16 + lrow) * BK + cA];
#pragma unroll
    for (int ms = 0; ms < 4; ++ms)
#pragma unroll
      for (int ns = 0; ns < 4; ++ns)
        acc[ms][ns] = __builtin_amdgcn_mfma_f32_16x16x32_f16(af[ms], bf[ns], acc[ms][ns], 0, 0, 0);
    __syncthreads();
  }

#pragma unroll
  for (int ms = 0; ms < 4; ++ms)
#pragma unroll
    for (int ns = 0; ns < 4; ++ns)
#pragma unroll
      for (int r = 0; r < 4; ++r) {
        float v = acc[ms][ns][r];
        const int rl = wm * 64 + ms * 16 + quad * 4 + r;
        const int h = n0 + wn * 64 + ns * 16 + lrow;
        const int m = m0 + rl;
        if (gather) {
          if (m < cnt) {
            const int sl = base + m;
            atomicAdd(&out[(size_t)slott[sl] * HDIM + h], v * slotg[sl]);
          }
        } else {
          atomicAdd(&out[(size_t)m * HDIM + h], v);
        }
      }
}

// ---------------- launcher ----------------

extern "C" void kernel_launch(void* const* d_in, const int* in_sizes, int n_in,
                              void* d_out, int out_size, void* d_ws, size_t ws_size,
                              hipStream_t stream) {
  const float* x    = (const float*)d_in[0];
  const float* gw   = (const float*)d_in[1];
  const float* bias = (const float*)d_in[2];
  const float* ws1  = (const float*)d_in[3];
  const float* ws2  = (const float*)d_in[4];
  const float* ws3  = (const float*)d_in[5];
  const float* we1  = (const float*)d_in[6];
  const float* we2  = (const float*)d_in[7];
  const float* we3  = (const float*)d_in[8];
  float* out = (float*)d_out;

  char* ws = (char*)d_ws;
  _Float16* xb   = (_Float16*)(ws + WS_XB);
  _Float16* acts = (_Float16*)(ws + WS_ACT_S);
  _Float16* actr = (_Float16*)(ws + WS_ACT_R);
  int*   toke  = (int*)(ws + WS_TOKE);
  float* tokg  = (float*)(ws + WS_TOKG);
  int*   slott = (int*)(ws + WS_SLOTT);
  float* slotg = (float*)(ws + WS_SLOTG);
  int* counts  = (int*)(ws + WS_COUNTS);
  int* fill    = (int*)(ws + WS_FILL);
  int* offs    = (int*)(ws + WS_OFFS);
  _Float16* ws1h = (_Float16*)(ws + WS_WS1H);
  _Float16* ws3h = (_Float16*)(ws + WS_WS3H);
  _Float16* ws2h = (_Float16*)(ws + WS_WS2H);
  _Float16* we1h = (_Float16*)(ws + WS_WE1H);
  _Float16* we3h = (_Float16*)(ws + WS_WE3H);
  _Float16* we2h = (_Float16*)(ws + WS_WE2H);

  hipLaunchKernelGGL(zero_meta_kernel, dim3(1), dim3(64), 0, stream, counts);
  hipLaunchKernelGGL(gate_kernel, dim3(1024), dim3(256), 0, stream, x, gw, bias, xb, toke, tokg, counts);
  hipLaunchKernelGGL(offsets_kernel, dim3(1), dim3(64), 0, stream, counts, offs);
  hipLaunchKernelGGL(scatter_kernel, dim3(16), dim3(256), 0, stream, toke, tokg, offs, fill, slott, slotg);

  constexpr int GS = (FDIM * HDIM) / 2048;           // 1408
  constexpr int GR = (NEXP * FDIM * HDIM) / 2048;    // 11264
  hipLaunchKernelGGL(cvt3_kernel, dim3(GS, 3), dim3(256), 0, stream, ws1, ws3, ws2, ws1h, ws3h, ws2h);
  hipLaunchKernelGGL(cvt3_kernel, dim3(GR, 3), dim3(256), 0, stream, we1, we3, we2, we1h, we3h, we2h);

  hipMemsetAsync(out, 0, (size_t)TDIM * HDIM * sizeof(float), stream);

  // z = 0: shared expert (dense over all tokens); z = 1..8: routed expert z-1
  hipLaunchKernelGGL(up_kernel, dim3(FDIM / 128, TDIM / 128, NEXP + 1), dim3(256), 0, stream,
                     xb, ws1h, ws3h, we1h, we3h, acts, actr, counts, offs, slott);
  hipLaunchKernelGGL(down_kernel, dim3(HDIM / 128, TDIM / 128, NEXP + 1), dim3(256), 0, stream,
                     acts, actr, ws2h, we2h, out, counts, offs, slott, slotg);
}